// Round 14
// baseline (637.276 us; speedup 1.0000x reference)
//
#include <hip/hip_runtime.h>
#include <hip/hip_bf16.h>

#define N_NODES 100000
#define G_PART 16     // node groups; npg = 6250 -> 25 KB LDS hist
#define B_PART 96     // blocks per group; grid 1536 = 6 blocks/CU (LDS cap)
#define NPG_PAD 6272  // LDS capacity (>= ceil(N/G_PART))
#define A_BLOCKS 1024 // partition blocks

// ---------------------------------------------------------------- CSR build
// R5: device atomics are memory-side -> LDS hist. R6: occupancy. R7: don't
// pollute L2 with the stream. R8: radix partition, edges read ~once.
// R12: ushort partials. R13: agg+gemm fused. R14: fused-kernel critical path.
__global__ __launch_bounds__(256) void partition_edges(
    const int* __restrict__ src, const int* __restrict__ dst, int E,
    int* __restrict__ bkt, unsigned int* __restrict__ gcur, int cap, int npg) {
    __shared__ int cnt16[G_PART];
    __shared__ unsigned int base16[G_PART];
    __shared__ unsigned int cur16[G_PART];
    int tid = threadIdx.x;
    if (tid < G_PART) cnt16[tid] = 0;
    __syncthreads();
    int per = (E + A_BLOCKS - 1) / A_BLOCKS;
    int beg = blockIdx.x * per;
    int end = min(beg + per, E);
    for (int i = beg + tid; i < end; i += 256) {
        int d = dst[i];
        atomicAdd(&cnt16[d / npg], 1);
    }
    __syncthreads();
    if (tid < G_PART) {
        base16[tid] = atomicAdd(&gcur[tid], (unsigned int)cnt16[tid]);
        cur16[tid] = 0;
    }
    __syncthreads();
    for (int i = beg + tid; i < end; i += 256) {
        int d = dst[i];
        int s = src[i];
        int g = d / npg;
        unsigned int p = base16[g] + atomicAdd(&cur16[g], 1u);
        bkt[(size_t)g * cap + p] = ((d - g * npg) << 17) | s;
    }
}

__global__ __launch_bounds__(256) void count_hist(const int* __restrict__ bkt,
                                                  const unsigned int* __restrict__ gcur,
                                                  int cap, unsigned short* __restrict__ partial,
                                                  int npg, int N) {
    __shared__ int hist[NPG_PAD];
    int g = blockIdx.x & (G_PART - 1);
    int b = blockIdx.x / G_PART;
    int tid = threadIdx.x;
    for (int i = tid; i < npg; i += 256) hist[i] = 0;
    __syncthreads();
    int len = (int)gcur[g];
    int per = (len + B_PART - 1) / B_PART;
    int ibeg = b * per;
    int iend = min(ibeg + per, len);
    const int* bp = bkt + (size_t)g * cap;
    for (int i = ibeg + tid; i < iend; i += 256) {
        int v = __builtin_nontemporal_load(bp + i);
        atomicAdd(&hist[v >> 17], 1);
    }
    __syncthreads();
    size_t base = (size_t)(g * B_PART + b) * npg;
    for (int j = tid; j < npg; j += 256) partial[base + j] = (unsigned short)hist[j];
}

__global__ __launch_bounds__(256) void scan_partials(unsigned short* __restrict__ partial,
                                                     int* __restrict__ cnt,
                                                     int npg, int N) {
    int n = blockIdx.x * 256 + threadIdx.x;
    if (n >= N) return;
    int g = n / npg;
    int i = n - g * npg;
    size_t base = (size_t)g * B_PART * npg + i;
    int run = 0;
#pragma unroll 4
    for (int b = 0; b < B_PART; ++b) {
        size_t idx = base + (size_t)b * npg;
        int t = partial[idx];
        partial[idx] = (unsigned short)run;
        run += t;
    }
    cnt[n] = run;
}

__global__ __launch_bounds__(256) void fill_hist(const int* __restrict__ bkt,
                                                 const unsigned int* __restrict__ gcur,
                                                 int cap,
                                                 const unsigned short* __restrict__ partial,
                                                 const int* __restrict__ row_off,
                                                 int* __restrict__ csr_src,
                                                 int npg, int N) {
    __shared__ int cur[NPG_PAD];
    int g = blockIdx.x & (G_PART - 1);
    int b = blockIdx.x / G_PART;
    int lo = g * npg;
    int tid = threadIdx.x;
    size_t pbase = (size_t)(g * B_PART + b) * npg;
    for (int i = tid; i < npg && lo + i < N; i += 256)
        cur[i] = row_off[lo + i] + (int)partial[pbase + i];
    __syncthreads();
    int len = (int)gcur[g];
    int per = (len + B_PART - 1) / B_PART;
    int ibeg = b * per;
    int iend = min(ibeg + per, len);
    const int* bp = bkt + (size_t)g * cap;
    for (int i = ibeg + tid; i < iend; i += 256) {
        int v = __builtin_nontemporal_load(bp + i);
        int p = atomicAdd(&cur[v >> 17], 1);
        csr_src[p] = v & 0x1FFFF;
    }
}

// ---------------- grid-parallel exclusive scan (3 kernels, 1024 elems/block)
#define SCHUNK 1024

__global__ __launch_bounds__(256) void scan_blocks(const int* __restrict__ cnt,
                                                   int* __restrict__ row_off,
                                                   int* __restrict__ block_sums, int n) {
    __shared__ int ts[256];
    int tid = threadIdx.x;
    int base = blockIdx.x * SCHUNK + tid * 4;
    int v[4];
    int s = 0;
#pragma unroll
    for (int j = 0; j < 4; ++j) {
        int i = base + j;
        v[j] = (i < n) ? cnt[i] : 0;
        s += v[j];
    }
    ts[tid] = s;
    __syncthreads();
    for (int off = 1; off < 256; off <<= 1) {
        int t = 0;
        if (tid >= off) t = ts[tid - off];
        __syncthreads();
        if (tid >= off) ts[tid] += t;
        __syncthreads();
    }
    int run = (tid > 0) ? ts[tid - 1] : 0;
    if (tid == 255) block_sums[blockIdx.x] = ts[255];
#pragma unroll
    for (int j = 0; j < 4; ++j) {
        int i = base + j;
        if (i < n) row_off[i] = run;
        run += v[j];
    }
}

__global__ __launch_bounds__(256) void scan_sums(int* __restrict__ block_sums, int nb,
                                                 int* __restrict__ row_off, int n) {
    __shared__ int ts[256];
    int tid = threadIdx.x;
    int v = (tid < nb) ? block_sums[tid] : 0;
    ts[tid] = v;
    __syncthreads();
    for (int off = 1; off < 256; off <<= 1) {
        int t = 0;
        if (tid >= off) t = ts[tid - off];
        __syncthreads();
        if (tid >= off) ts[tid] += t;
        __syncthreads();
    }
    if (tid < nb) block_sums[tid] = (tid > 0) ? ts[tid - 1] : 0;
    if (tid == 255) row_off[n] = ts[255];
}

__global__ __launch_bounds__(256) void scan_add(int* __restrict__ row_off,
                                                const int* __restrict__ block_sums, int n) {
    int tid = threadIdx.x;
    int off = block_sums[blockIdx.x];
    int base = blockIdx.x * SCHUNK + tid * 4;
#pragma unroll
    for (int j = 0; j < 4; ++j) {
        int i = base + j;
        if (i < n) row_off[i] += off;
    }
}

// ---------------------------------------------------------------- bf16 packs
__global__ __launch_bounds__(256) void pack_bf16(const float* __restrict__ in,
                                                 uint2* __restrict__ out, int n4) {
    int i = blockIdx.x * 256 + threadIdx.x;
    if (i >= n4) return;
    float4 v = *(const float4*)&in[(size_t)i * 4];
    __hip_bfloat162 p0 = __float22bfloat162_rn(make_float2(v.x, v.y));
    __hip_bfloat162 p1 = __float22bfloat162_rn(make_float2(v.z, v.w));
    uint2 o;
    o.x = *(const uint*)&p0;
    o.y = *(const uint*)&p1;
    out[i] = o;
}

static __device__ inline unsigned short f2bf(float v) {
    __hip_bfloat16 b = __float2bfloat16(v);
    return *(const unsigned short*)&b;
}

// all weights in one launch: Wc1/Wc2 [128][256] ([Wl|Wr]); W3c [16][128]
__global__ __launch_bounds__(256) void pack_weights(
    const float* __restrict__ Wl1, const float* __restrict__ Wr1,
    const float* __restrict__ Wl2, const float* __restrict__ Wr2,
    const float* __restrict__ Wl3, const float* __restrict__ Wr3,
    unsigned short* __restrict__ Wc1, unsigned short* __restrict__ Wc2,
    unsigned short* __restrict__ W3c) {
    int idx = blockIdx.x * 256 + threadIdx.x;
    if (idx < 32768) {
        int n = idx >> 8, k = idx & 255;
        Wc1[idx] = f2bf((k < 128) ? Wl1[n * 128 + k] : Wr1[n * 128 + (k - 128)]);
    } else if (idx < 65536) {
        int t = idx - 32768;
        int n = t >> 8, k = t & 255;
        Wc2[t] = f2bf((k < 128) ? Wl2[n * 128 + k] : Wr2[n * 128 + (k - 128)]);
    } else if (idx < 65536 + 2048) {
        int t = idx - 65536;
        int n = t >> 7, k = t & 127;
        float v = (n < 6) ? Wl3[n * 128 + k] : ((n < 12) ? Wr3[(n - 6) * 128 + k] : 0.f);
        W3c[t] = f2bf(v);
    }
}

// --------------------------------------------- fused agg + MFMA GEMM (+lin3)
// R13: per block of 16 nodes: gather mean-agg rows into LDS, then MFMA tile.
// R14: shrink post-barrier critical path — prefetch self-half A frags + bias
// under the gather's shadow; epilogue staged in LDS and dumped with one
// cooperative uint4 store round (was scattered 2B stores); nt csr loads.
typedef __attribute__((ext_vector_type(8))) short bfrag8;
typedef __attribute__((ext_vector_type(4))) float f32x4;

static __device__ inline float2 unpack2(uint v) {
    float2 r;
    r.x = __uint_as_float(v << 16);
    r.y = __uint_as_float(v & 0xffff0000u);
    return r;
}

__global__ __launch_bounds__(256) void agg_gemm(
    const uint* __restrict__ featb,           // [N][64] bf16x2 gather table
    const unsigned short* __restrict__ Aself, // [M][128] bf16 self rows
    const int* __restrict__ row_off,
    const int* __restrict__ csr,
    const unsigned short* __restrict__ Wc,    // [128][256] bf16
    const float* __restrict__ bias,           // [128]
    unsigned short* __restrict__ outb,        // [M][128] bf16 (nullable)
    int do_lin3,
    const unsigned short* __restrict__ W3c,   // [16][128] bf16
    const float* __restrict__ b3,             // [6]
    unsigned short* __restrict__ zg,          // [M][8] bf16
    float* __restrict__ zs,                   // [M][6] fp32
    int M, int relu) {
    __shared__ unsigned short aggT[16][136];  // +8 pad
    __shared__ unsigned short h2T[16][136];
    int tid = threadIdx.x;
    int wave = tid >> 6;
    int lane = tid & 63;
    int tile = blockIdx.x * 16;
    int mrow = lane & 15;
    int quad = lane >> 4;
    int row = tile + mrow;
    int rc = (row < M) ? row : 0;

    // ---- prefetch (completes under the gather's shadow)
    bfrag8 aself[4];
    const unsigned short* arow1 = Aself + (size_t)rc * 128;
#pragma unroll
    for (int ks = 0; ks < 4; ++ks)
        aself[ks] = *(const bfrag8*)(arow1 + ks * 32 + quad * 8);
    int t0 = wave * 2, t1 = wave * 2 + 1;
    float bc0 = bias[t0 * 16 + mrow];
    float bc1 = bias[t1 * 16 + mrow];

    // ---- phase 1: gather (4 nodes per wave, sequential; R9 inner loop)
    for (int sub = 0; sub < 4; ++sub) {
        int node = tile + wave * 4 + sub;
        float sx = 0.f, sy = 0.f;
        float inv = 0.f;
        if (node < M) {
            int beg = row_off[node], end = row_off[node + 1];
            int i = beg;
            for (; i + 4 <= end; i += 4) {
                int s0 = __builtin_nontemporal_load(csr + i);
                int s1 = __builtin_nontemporal_load(csr + i + 1);
                int s2 = __builtin_nontemporal_load(csr + i + 2);
                int s3 = __builtin_nontemporal_load(csr + i + 3);
                uint v0 = featb[(size_t)s0 * 64 + lane];
                uint v1 = featb[(size_t)s1 * 64 + lane];
                uint v2 = featb[(size_t)s2 * 64 + lane];
                uint v3 = featb[(size_t)s3 * 64 + lane];
                float2 f0 = unpack2(v0), f1 = unpack2(v1);
                float2 f2 = unpack2(v2), f3 = unpack2(v3);
                sx += f0.x + f1.x + f2.x + f3.x;
                sy += f0.y + f1.y + f2.y + f3.y;
            }
            for (; i < end; ++i) {
                uint v = featb[(size_t)__builtin_nontemporal_load(csr + i) * 64 + lane];
                float2 f = unpack2(v);
                sx += f.x;
                sy += f.y;
            }
            inv = (end > beg) ? 1.0f / (float)(end - beg) : 0.0f;
        }
        __hip_bfloat162 p = __float22bfloat162_rn(make_float2(sx * inv, sy * inv));
        *(uint*)&aggT[wave * 4 + sub][lane * 2] = *(const uint*)&p;
    }
    __syncthreads();

    // ---- phase 2: MFMA tile. wave w covers cols 32w..32w+31 (t = 2w, 2w+1)
    f32x4 acc0 = (f32x4){0.f, 0.f, 0.f, 0.f};
    f32x4 acc1 = (f32x4){0.f, 0.f, 0.f, 0.f};
#pragma unroll
    for (int ks = 0; ks < 8; ++ks) {
        bfrag8 af;
        if (ks < 4) af = *(const bfrag8*)&aggT[mrow][ks * 32 + quad * 8];
        else af = aself[ks - 4];
        bfrag8 bf0 = *(const bfrag8*)(Wc + (size_t)(t0 * 16 + mrow) * 256 + ks * 32 + quad * 8);
        bfrag8 bf1 = *(const bfrag8*)(Wc + (size_t)(t1 * 16 + mrow) * 256 + ks * 32 + quad * 8);
        acc0 = __builtin_amdgcn_mfma_f32_16x16x32_bf16(af, bf0, acc0, 0, 0, 0);
        acc1 = __builtin_amdgcn_mfma_f32_16x16x32_bf16(af, bf1, acc1, 0, 0, 0);
    }
    // epilogue: stage C tile in LDS (C layout: col within tile = mrow, row = quad*4+r)
#pragma unroll
    for (int tt = 0; tt < 2; ++tt) {
        f32x4 a = tt ? acc1 : acc0;
        int col = (wave * 2 + tt) * 16 + mrow;
        float bc = tt ? bc1 : bc0;
#pragma unroll
        for (int r = 0; r < 4; ++r) {
            float v = a[r] + bc;
            if (relu) v = fmaxf(v, 0.f);
            h2T[quad * 4 + r][col] = f2bf(v);
        }
    }
    __syncthreads();
    // cooperative coalesced dump: 16 rows x 128 ushort, uint4 per thread
    if (outb) {
        int r = tid >> 4;
        int c8 = (tid & 15) * 8;
        int orow = tile + r;
        if (orow < M)
            *(uint4*)&outb[(size_t)orow * 128 + c8] = *(const uint4*)&h2T[r][c8];
    }
    // ---- fused lin3 (layer 2 only): one 16x16 tile, K=128, from h2T
    if (do_lin3 && wave == 0) {
        f32x4 acc = (f32x4){0.f, 0.f, 0.f, 0.f};
#pragma unroll
        for (int ks = 0; ks < 4; ++ks) {
            bfrag8 af = *(const bfrag8*)&h2T[mrow][ks * 32 + quad * 8];
            bfrag8 bf = *(const bfrag8*)(W3c + (size_t)mrow * 128 + ks * 32 + quad * 8);
            acc = __builtin_amdgcn_mfma_f32_16x16x32_bf16(af, bf, acc, 0, 0, 0);
        }
        int col = mrow;
#pragma unroll
        for (int r = 0; r < 4; ++r) {
            int orow = tile + quad * 4 + r;
            if (orow < M) {
                float v = acc[r];
                if (col < 6) {
                    zg[(size_t)orow * 8 + col] = f2bf(v);
                } else if (col < 12) {
                    zs[(size_t)orow * 6 + (col - 6)] = v + b3[col - 6];
                }
            }
        }
    }
}

// ------------------------------------------- final: out[n][j] = mean_s zg[s][j] + zs[n][j]
__global__ void out_kernel(const unsigned short* __restrict__ zg,
                           const float* __restrict__ zs,
                           const int* __restrict__ row_off,
                           const int* __restrict__ csr,
                           float* __restrict__ out, int M) {
    int idx = blockIdx.x * blockDim.x + threadIdx.x;
    int node = idx >> 3;
    int j = idx & 7;
    if (node >= M || j >= 6) return;
    int beg = row_off[node], end = row_off[node + 1];
    float acc = 0.f;
    int i = beg;
    for (; i + 4 <= end; i += 4) {
        int s0 = __builtin_nontemporal_load(csr + i);
        int s1 = __builtin_nontemporal_load(csr + i + 1);
        int s2 = __builtin_nontemporal_load(csr + i + 2);
        int s3 = __builtin_nontemporal_load(csr + i + 3);
        uint z0 = zg[(size_t)s0 * 8 + j];
        uint z1 = zg[(size_t)s1 * 8 + j];
        uint z2 = zg[(size_t)s2 * 8 + j];
        uint z3 = zg[(size_t)s3 * 8 + j];
        acc += __uint_as_float(z0 << 16) + __uint_as_float(z1 << 16) +
               __uint_as_float(z2 << 16) + __uint_as_float(z3 << 16);
    }
    for (; i < end; ++i) {
        uint z = zg[(size_t)__builtin_nontemporal_load(csr + i) * 8 + j];
        acc += __uint_as_float(z << 16);
    }
    float inv = (end > beg) ? 1.0f / (float)(end - beg) : 0.0f;
    out[(size_t)node * 6 + j] = acc * inv + zs[(size_t)node * 6 + j];
}

// ---------------------------------------------------------------- launch
static inline size_t align_up(size_t x, size_t a) { return (x + a - 1) & ~(a - 1); }

extern "C" void kernel_launch(void* const* d_in, const int* in_sizes, int n_in,
                              void* d_out, int out_size, void* d_ws, size_t ws_size,
                              hipStream_t stream) {
    const float* x = (const float*)d_in[0];
    const int* ei = (const int*)d_in[1];
    const float* Wl1 = (const float*)d_in[2];
    const float* Wr1 = (const float*)d_in[3];
    const float* b1 = (const float*)d_in[4];
    const float* Wl2 = (const float*)d_in[5];
    const float* Wr2 = (const float*)d_in[6];
    const float* b2 = (const float*)d_in[7];
    const float* Wl3 = (const float*)d_in[8];
    const float* Wr3 = (const float*)d_in[9];
    const float* b3 = (const float*)d_in[10];

    const int N = in_sizes[0] / 128;   // 100000
    const int E = in_sizes[1] / 2;     // 3200000
    const int* src = ei;
    const int* dst = ei + E;

    // workspace layout
    char* ws = (char*)d_ws;
    size_t off = 0;
    int* cnt = (int*)(ws + off);        off = align_up(off + (size_t)N * 4, 512);
    int* row_off = (int*)(ws + off);    off = align_up(off + (size_t)(N + 1) * 4, 512);
    int* block_sums = (int*)(ws + off); off = align_up(off + 512 * 4, 512);
    unsigned int* gcur = (unsigned int*)(ws + off); off = align_up(off + 64 * 4, 512);
    unsigned short* Wc1 = (unsigned short*)(ws + off); off = align_up(off + 128 * 256 * 2, 512);
    unsigned short* Wc2 = (unsigned short*)(ws + off); off = align_up(off + 128 * 256 * 2, 512);
    unsigned short* W3c = (unsigned short*)(ws + off); off = align_up(off + 16 * 128 * 2, 512);
    int* csr_src = (int*)(ws + off);    off = align_up(off + (size_t)E * 4, 512);
    float* slotA = (float*)(ws + off);  off = align_up(off + (size_t)N * 128 * 4, 512);
    float* slotB = (float*)(ws + off);  off = align_up(off + (size_t)N * 128 * 4, 512);
    uint2* h1b = (uint2*)(ws + off);    off = align_up(off + (size_t)N * 128 * 2, 512);
    // aliases (lifetimes disjoint):
    //  slotA: partial ushort [count..fill] (19.2MB); xb [pack..agg_gemm1] (25.6MB)
    //  slotB: bkt [partition..fill] (13.44MB); zg+zs [agg_gemm2..out] (4MB)
    unsigned short* partial = (unsigned short*)slotA;
    const int cap = 210000;
    int* bkt = (int*)slotB;
    uint2* xb = (uint2*)slotA;          // written after fill (partial dead)
    unsigned short* zg = (unsigned short*)slotB;
    float* zs = (float*)((char*)slotB + align_up((size_t)N * 8 * 2, 512));
    (void)ws_size;

    // --- CSR build: radix partition + LDS histogram, no per-edge global atomics
    const int npg = (N + G_PART - 1) / G_PART;       // 6250
    const int build_grid = G_PART * B_PART;          // 1536 = 6 blocks/CU

    hipMemsetAsync(gcur, 0, G_PART * 4, stream);
    partition_edges<<<A_BLOCKS, 256, 0, stream>>>(src, dst, E, bkt, gcur, cap, npg);
    count_hist<<<build_grid, 256, 0, stream>>>(bkt, gcur, cap, partial, npg, N);
    scan_partials<<<(N + 255) / 256, 256, 0, stream>>>(partial, cnt, npg, N);

    const int nscan = (N + SCHUNK - 1) / SCHUNK;
    scan_blocks<<<nscan, 256, 0, stream>>>(cnt, row_off, block_sums, N);
    scan_sums<<<1, 256, 0, stream>>>(block_sums, nscan, row_off, N);
    scan_add<<<nscan, 256, 0, stream>>>(row_off, block_sums, N);

    fill_hist<<<build_grid, 256, 0, stream>>>(bkt, gcur, cap, partial, row_off,
                                              csr_src, npg, N);

    // packs (xb after fill: partial slot is free)
    const int n4 = N * 32;
    pack_bf16<<<(n4 + 255) / 256, 256, 0, stream>>>(x, xb, n4);
    pack_weights<<<(65536 + 2048 + 255) / 256, 256, 0, stream>>>(
        Wl1, Wr1, Wl2, Wr2, Wl3, Wr3, Wc1, Wc2, W3c);

    int fusedGrid = (N + 15) / 16;   // 6250 blocks

    // layer 1: fused gather+GEMM -> h1b (bf16)
    agg_gemm<<<fusedGrid, 256, 0, stream>>>(
        (const uint*)xb, (const unsigned short*)xb, row_off, csr_src, Wc1, b1,
        (unsigned short*)h1b, 0, nullptr, nullptr, nullptr, nullptr, N, 1);
    // layer 2: fused gather+GEMM+lin3 -> zg (bf16) + zs (fp32); h2 never stored
    agg_gemm<<<fusedGrid, 256, 0, stream>>>(
        (const uint*)h1b, (const unsigned short*)h1b, row_off, csr_src, Wc2, b2,
        nullptr, 1, W3c, b3, zg, zs, N, 1);
    // final
    out_kernel<<<(N * 8 + 255) / 256, 256, 0, stream>>>(zg, zs, row_off, csr_src,
                                                        (float*)d_out, N);
}

// Round 15
// 575.086 us; speedup vs baseline: 1.1081x; 1.1081x over previous
//
#include <hip/hip_runtime.h>
#include <hip/hip_bf16.h>

#define N_NODES 100000
#define G_PART 16     // node groups; npg = 6250 -> 25 KB LDS hist
#define B_PART 96     // blocks per group; grid 1536 = 6 blocks/CU (LDS cap)
#define NPG_PAD 6272  // LDS capacity (>= ceil(N/G_PART))
#define A_BLOCKS 1024 // partition blocks

// ---------------------------------------------------------------- CSR build
// R5: device atomics are memory-side -> LDS hist. R6: occupancy. R7: don't
// pollute L2 with the stream. R8: radix partition, edges read ~once.
// R12: ushort partials. R13: agg+gemm fused. R14 lesson: nt on sequential
// csr loads re-fetches each 64B line ~4x (FETCH +41MB) — csr loads must be
// plain cached loads. nt stays ONLY on the bkt stream (read exactly once).
__global__ __launch_bounds__(256) void partition_edges(
    const int* __restrict__ src, const int* __restrict__ dst, int E,
    int* __restrict__ bkt, unsigned int* __restrict__ gcur, int cap, int npg) {
    __shared__ int cnt16[G_PART];
    __shared__ unsigned int base16[G_PART];
    __shared__ unsigned int cur16[G_PART];
    int tid = threadIdx.x;
    if (tid < G_PART) cnt16[tid] = 0;
    __syncthreads();
    int per = (E + A_BLOCKS - 1) / A_BLOCKS;
    int beg = blockIdx.x * per;
    int end = min(beg + per, E);
    for (int i = beg + tid; i < end; i += 256) {
        int d = dst[i];
        atomicAdd(&cnt16[d / npg], 1);
    }
    __syncthreads();
    if (tid < G_PART) {
        base16[tid] = atomicAdd(&gcur[tid], (unsigned int)cnt16[tid]);
        cur16[tid] = 0;
    }
    __syncthreads();
    for (int i = beg + tid; i < end; i += 256) {
        int d = dst[i];
        int s = src[i];
        int g = d / npg;
        unsigned int p = base16[g] + atomicAdd(&cur16[g], 1u);
        bkt[(size_t)g * cap + p] = ((d - g * npg) << 17) | s;
    }
}

__global__ __launch_bounds__(256) void count_hist(const int* __restrict__ bkt,
                                                  const unsigned int* __restrict__ gcur,
                                                  int cap, unsigned short* __restrict__ partial,
                                                  int npg, int N) {
    __shared__ int hist[NPG_PAD];
    int g = blockIdx.x & (G_PART - 1);
    int b = blockIdx.x / G_PART;
    int tid = threadIdx.x;
    for (int i = tid; i < npg; i += 256) hist[i] = 0;
    __syncthreads();
    int len = (int)gcur[g];
    int per = (len + B_PART - 1) / B_PART;
    int ibeg = b * per;
    int iend = min(ibeg + per, len);
    const int* bp = bkt + (size_t)g * cap;
    for (int i = ibeg + tid; i < iend; i += 256) {
        int v = __builtin_nontemporal_load(bp + i);
        atomicAdd(&hist[v >> 17], 1);
    }
    __syncthreads();
    size_t base = (size_t)(g * B_PART + b) * npg;
    for (int j = tid; j < npg; j += 256) partial[base + j] = (unsigned short)hist[j];
}

__global__ __launch_bounds__(256) void scan_partials(unsigned short* __restrict__ partial,
                                                     int* __restrict__ cnt,
                                                     int npg, int N) {
    int n = blockIdx.x * 256 + threadIdx.x;
    if (n >= N) return;
    int g = n / npg;
    int i = n - g * npg;
    size_t base = (size_t)g * B_PART * npg + i;
    int run = 0;
#pragma unroll 4
    for (int b = 0; b < B_PART; ++b) {
        size_t idx = base + (size_t)b * npg;
        int t = partial[idx];
        partial[idx] = (unsigned short)run;
        run += t;
    }
    cnt[n] = run;
}

__global__ __launch_bounds__(256) void fill_hist(const int* __restrict__ bkt,
                                                 const unsigned int* __restrict__ gcur,
                                                 int cap,
                                                 const unsigned short* __restrict__ partial,
                                                 const int* __restrict__ row_off,
                                                 int* __restrict__ csr_src,
                                                 int npg, int N) {
    __shared__ int cur[NPG_PAD];
    int g = blockIdx.x & (G_PART - 1);
    int b = blockIdx.x / G_PART;
    int lo = g * npg;
    int tid = threadIdx.x;
    size_t pbase = (size_t)(g * B_PART + b) * npg;
    for (int i = tid; i < npg && lo + i < N; i += 256)
        cur[i] = row_off[lo + i] + (int)partial[pbase + i];
    __syncthreads();
    int len = (int)gcur[g];
    int per = (len + B_PART - 1) / B_PART;
    int ibeg = b * per;
    int iend = min(ibeg + per, len);
    const int* bp = bkt + (size_t)g * cap;
    for (int i = ibeg + tid; i < iend; i += 256) {
        int v = __builtin_nontemporal_load(bp + i);
        int p = atomicAdd(&cur[v >> 17], 1);
        csr_src[p] = v & 0x1FFFF;
    }
}

// ---------------- grid-parallel exclusive scan (3 kernels, 1024 elems/block)
#define SCHUNK 1024

__global__ __launch_bounds__(256) void scan_blocks(const int* __restrict__ cnt,
                                                   int* __restrict__ row_off,
                                                   int* __restrict__ block_sums, int n) {
    __shared__ int ts[256];
    int tid = threadIdx.x;
    int base = blockIdx.x * SCHUNK + tid * 4;
    int v[4];
    int s = 0;
#pragma unroll
    for (int j = 0; j < 4; ++j) {
        int i = base + j;
        v[j] = (i < n) ? cnt[i] : 0;
        s += v[j];
    }
    ts[tid] = s;
    __syncthreads();
    for (int off = 1; off < 256; off <<= 1) {
        int t = 0;
        if (tid >= off) t = ts[tid - off];
        __syncthreads();
        if (tid >= off) ts[tid] += t;
        __syncthreads();
    }
    int run = (tid > 0) ? ts[tid - 1] : 0;
    if (tid == 255) block_sums[blockIdx.x] = ts[255];
#pragma unroll
    for (int j = 0; j < 4; ++j) {
        int i = base + j;
        if (i < n) row_off[i] = run;
        run += v[j];
    }
}

__global__ __launch_bounds__(256) void scan_sums(int* __restrict__ block_sums, int nb,
                                                 int* __restrict__ row_off, int n) {
    __shared__ int ts[256];
    int tid = threadIdx.x;
    int v = (tid < nb) ? block_sums[tid] : 0;
    ts[tid] = v;
    __syncthreads();
    for (int off = 1; off < 256; off <<= 1) {
        int t = 0;
        if (tid >= off) t = ts[tid - off];
        __syncthreads();
        if (tid >= off) ts[tid] += t;
        __syncthreads();
    }
    if (tid < nb) block_sums[tid] = (tid > 0) ? ts[tid - 1] : 0;
    if (tid == 255) row_off[n] = ts[255];
}

__global__ __launch_bounds__(256) void scan_add(int* __restrict__ row_off,
                                                const int* __restrict__ block_sums, int n) {
    int tid = threadIdx.x;
    int off = block_sums[blockIdx.x];
    int base = blockIdx.x * SCHUNK + tid * 4;
#pragma unroll
    for (int j = 0; j < 4; ++j) {
        int i = base + j;
        if (i < n) row_off[i] += off;
    }
}

// ---------------------------------------------------------------- bf16 packs
__global__ __launch_bounds__(256) void pack_bf16(const float* __restrict__ in,
                                                 uint2* __restrict__ out, int n4) {
    int i = blockIdx.x * 256 + threadIdx.x;
    if (i >= n4) return;
    float4 v = *(const float4*)&in[(size_t)i * 4];
    __hip_bfloat162 p0 = __float22bfloat162_rn(make_float2(v.x, v.y));
    __hip_bfloat162 p1 = __float22bfloat162_rn(make_float2(v.z, v.w));
    uint2 o;
    o.x = *(const uint*)&p0;
    o.y = *(const uint*)&p1;
    out[i] = o;
}

static __device__ inline unsigned short f2bf(float v) {
    __hip_bfloat16 b = __float2bfloat16(v);
    return *(const unsigned short*)&b;
}

// all weights in one launch: Wc1/Wc2 [128][256] ([Wl|Wr]); W3c [16][128]
__global__ __launch_bounds__(256) void pack_weights(
    const float* __restrict__ Wl1, const float* __restrict__ Wr1,
    const float* __restrict__ Wl2, const float* __restrict__ Wr2,
    const float* __restrict__ Wl3, const float* __restrict__ Wr3,
    unsigned short* __restrict__ Wc1, unsigned short* __restrict__ Wc2,
    unsigned short* __restrict__ W3c) {
    int idx = blockIdx.x * 256 + threadIdx.x;
    if (idx < 32768) {
        int n = idx >> 8, k = idx & 255;
        Wc1[idx] = f2bf((k < 128) ? Wl1[n * 128 + k] : Wr1[n * 128 + (k - 128)]);
    } else if (idx < 65536) {
        int t = idx - 32768;
        int n = t >> 8, k = t & 255;
        Wc2[t] = f2bf((k < 128) ? Wl2[n * 128 + k] : Wr2[n * 128 + (k - 128)]);
    } else if (idx < 65536 + 2048) {
        int t = idx - 65536;
        int n = t >> 7, k = t & 127;
        float v = (n < 6) ? Wl3[n * 128 + k] : ((n < 12) ? Wr3[(n - 6) * 128 + k] : 0.f);
        W3c[t] = f2bf(v);
    }
}

// --------------------------------------------- fused agg + MFMA GEMM (+lin3)
// R13: per block of 16 nodes: gather mean-agg rows into LDS, then MFMA tile.
// R15 = R13 + R14's good parts only: prefetch self A-frags + bias under the
// gather's shadow; LDS-staged coalesced uint4 epilogue. csr loads are PLAIN
// (cached) — R14 proved nt on them re-fetches lines ~4x.
typedef __attribute__((ext_vector_type(8))) short bfrag8;
typedef __attribute__((ext_vector_type(4))) float f32x4;

static __device__ inline float2 unpack2(uint v) {
    float2 r;
    r.x = __uint_as_float(v << 16);
    r.y = __uint_as_float(v & 0xffff0000u);
    return r;
}

__global__ __launch_bounds__(256) void agg_gemm(
    const uint* __restrict__ featb,           // [N][64] bf16x2 gather table
    const unsigned short* __restrict__ Aself, // [M][128] bf16 self rows
    const int* __restrict__ row_off,
    const int* __restrict__ csr,
    const unsigned short* __restrict__ Wc,    // [128][256] bf16
    const float* __restrict__ bias,           // [128]
    unsigned short* __restrict__ outb,        // [M][128] bf16 (nullable)
    int do_lin3,
    const unsigned short* __restrict__ W3c,   // [16][128] bf16
    const float* __restrict__ b3,             // [6]
    unsigned short* __restrict__ zg,          // [M][8] bf16
    float* __restrict__ zs,                   // [M][6] fp32
    int M, int relu) {
    __shared__ unsigned short aggT[16][136];  // +8 pad
    __shared__ unsigned short h2T[16][136];
    int tid = threadIdx.x;
    int wave = tid >> 6;
    int lane = tid & 63;
    int tile = blockIdx.x * 16;
    int mrow = lane & 15;
    int quad = lane >> 4;
    int row = tile + mrow;
    int rc = (row < M) ? row : 0;

    // ---- prefetch (completes under the gather's shadow)
    bfrag8 aself[4];
    const unsigned short* arow1 = Aself + (size_t)rc * 128;
#pragma unroll
    for (int ks = 0; ks < 4; ++ks)
        aself[ks] = *(const bfrag8*)(arow1 + ks * 32 + quad * 8);
    int t0 = wave * 2, t1 = wave * 2 + 1;
    float bc0 = bias[t0 * 16 + mrow];
    float bc1 = bias[t1 * 16 + mrow];

    // ---- phase 1: gather (4 nodes per wave, sequential; R9 inner loop)
    for (int sub = 0; sub < 4; ++sub) {
        int node = tile + wave * 4 + sub;
        float sx = 0.f, sy = 0.f;
        float inv = 0.f;
        if (node < M) {
            int beg = row_off[node], end = row_off[node + 1];
            int i = beg;
            for (; i + 4 <= end; i += 4) {
                int s0 = csr[i], s1 = csr[i + 1], s2 = csr[i + 2], s3 = csr[i + 3];
                uint v0 = featb[(size_t)s0 * 64 + lane];
                uint v1 = featb[(size_t)s1 * 64 + lane];
                uint v2 = featb[(size_t)s2 * 64 + lane];
                uint v3 = featb[(size_t)s3 * 64 + lane];
                float2 f0 = unpack2(v0), f1 = unpack2(v1);
                float2 f2 = unpack2(v2), f3 = unpack2(v3);
                sx += f0.x + f1.x + f2.x + f3.x;
                sy += f0.y + f1.y + f2.y + f3.y;
            }
            for (; i < end; ++i) {
                uint v = featb[(size_t)csr[i] * 64 + lane];
                float2 f = unpack2(v);
                sx += f.x;
                sy += f.y;
            }
            inv = (end > beg) ? 1.0f / (float)(end - beg) : 0.0f;
        }
        __hip_bfloat162 p = __float22bfloat162_rn(make_float2(sx * inv, sy * inv));
        *(uint*)&aggT[wave * 4 + sub][lane * 2] = *(const uint*)&p;
    }
    __syncthreads();

    // ---- phase 2: MFMA tile. wave w covers cols 32w..32w+31 (t = 2w, 2w+1)
    f32x4 acc0 = (f32x4){0.f, 0.f, 0.f, 0.f};
    f32x4 acc1 = (f32x4){0.f, 0.f, 0.f, 0.f};
#pragma unroll
    for (int ks = 0; ks < 8; ++ks) {
        bfrag8 af;
        if (ks < 4) af = *(const bfrag8*)&aggT[mrow][ks * 32 + quad * 8];
        else af = aself[ks - 4];
        bfrag8 bf0 = *(const bfrag8*)(Wc + (size_t)(t0 * 16 + mrow) * 256 + ks * 32 + quad * 8);
        bfrag8 bf1 = *(const bfrag8*)(Wc + (size_t)(t1 * 16 + mrow) * 256 + ks * 32 + quad * 8);
        acc0 = __builtin_amdgcn_mfma_f32_16x16x32_bf16(af, bf0, acc0, 0, 0, 0);
        acc1 = __builtin_amdgcn_mfma_f32_16x16x32_bf16(af, bf1, acc1, 0, 0, 0);
    }
    // epilogue: stage C tile in LDS (C layout: col within tile = mrow, row = quad*4+r)
#pragma unroll
    for (int tt = 0; tt < 2; ++tt) {
        f32x4 a = tt ? acc1 : acc0;
        int col = (wave * 2 + tt) * 16 + mrow;
        float bc = tt ? bc1 : bc0;
#pragma unroll
        for (int r = 0; r < 4; ++r) {
            float v = a[r] + bc;
            if (relu) v = fmaxf(v, 0.f);
            h2T[quad * 4 + r][col] = f2bf(v);
        }
    }
    __syncthreads();
    // cooperative coalesced dump: 16 rows x 128 ushort, uint4 per thread
    if (outb) {
        int r = tid >> 4;
        int c8 = (tid & 15) * 8;
        int orow = tile + r;
        if (orow < M)
            *(uint4*)&outb[(size_t)orow * 128 + c8] = *(const uint4*)&h2T[r][c8];
    }
    // ---- fused lin3 (layer 2 only): one 16x16 tile, K=128, from h2T
    if (do_lin3 && wave == 0) {
        f32x4 acc = (f32x4){0.f, 0.f, 0.f, 0.f};
#pragma unroll
        for (int ks = 0; ks < 4; ++ks) {
            bfrag8 af = *(const bfrag8*)&h2T[mrow][ks * 32 + quad * 8];
            bfrag8 bf = *(const bfrag8*)(W3c + (size_t)mrow * 128 + ks * 32 + quad * 8);
            acc = __builtin_amdgcn_mfma_f32_16x16x32_bf16(af, bf, acc, 0, 0, 0);
        }
        int col = mrow;
#pragma unroll
        for (int r = 0; r < 4; ++r) {
            int orow = tile + quad * 4 + r;
            if (orow < M) {
                float v = acc[r];
                if (col < 6) {
                    zg[(size_t)orow * 8 + col] = f2bf(v);
                } else if (col < 12) {
                    zs[(size_t)orow * 6 + (col - 6)] = v + b3[col - 6];
                }
            }
        }
    }
}

// ------------------------------------------- final: out[n][j] = mean_s zg[s][j] + zs[n][j]
__global__ void out_kernel(const unsigned short* __restrict__ zg,
                           const float* __restrict__ zs,
                           const int* __restrict__ row_off,
                           const int* __restrict__ csr,
                           float* __restrict__ out, int M) {
    int idx = blockIdx.x * blockDim.x + threadIdx.x;
    int node = idx >> 3;
    int j = idx & 7;
    if (node >= M || j >= 6) return;
    int beg = row_off[node], end = row_off[node + 1];
    float acc = 0.f;
    int i = beg;
    for (; i + 4 <= end; i += 4) {
        int s0 = csr[i], s1 = csr[i + 1], s2 = csr[i + 2], s3 = csr[i + 3];
        uint z0 = zg[(size_t)s0 * 8 + j];
        uint z1 = zg[(size_t)s1 * 8 + j];
        uint z2 = zg[(size_t)s2 * 8 + j];
        uint z3 = zg[(size_t)s3 * 8 + j];
        acc += __uint_as_float(z0 << 16) + __uint_as_float(z1 << 16) +
               __uint_as_float(z2 << 16) + __uint_as_float(z3 << 16);
    }
    for (; i < end; ++i) {
        uint z = zg[(size_t)csr[i] * 8 + j];
        acc += __uint_as_float(z << 16);
    }
    float inv = (end > beg) ? 1.0f / (float)(end - beg) : 0.0f;
    out[(size_t)node * 6 + j] = acc * inv + zs[(size_t)node * 6 + j];
}

// ---------------------------------------------------------------- launch
static inline size_t align_up(size_t x, size_t a) { return (x + a - 1) & ~(a - 1); }

extern "C" void kernel_launch(void* const* d_in, const int* in_sizes, int n_in,
                              void* d_out, int out_size, void* d_ws, size_t ws_size,
                              hipStream_t stream) {
    const float* x = (const float*)d_in[0];
    const int* ei = (const int*)d_in[1];
    const float* Wl1 = (const float*)d_in[2];
    const float* Wr1 = (const float*)d_in[3];
    const float* b1 = (const float*)d_in[4];
    const float* Wl2 = (const float*)d_in[5];
    const float* Wr2 = (const float*)d_in[6];
    const float* b2 = (const float*)d_in[7];
    const float* Wl3 = (const float*)d_in[8];
    const float* Wr3 = (const float*)d_in[9];
    const float* b3 = (const float*)d_in[10];

    const int N = in_sizes[0] / 128;   // 100000
    const int E = in_sizes[1] / 2;     // 3200000
    const int* src = ei;
    const int* dst = ei + E;

    // workspace layout
    char* ws = (char*)d_ws;
    size_t off = 0;
    int* cnt = (int*)(ws + off);        off = align_up(off + (size_t)N * 4, 512);
    int* row_off = (int*)(ws + off);    off = align_up(off + (size_t)(N + 1) * 4, 512);
    int* block_sums = (int*)(ws + off); off = align_up(off + 512 * 4, 512);
    unsigned int* gcur = (unsigned int*)(ws + off); off = align_up(off + 64 * 4, 512);
    unsigned short* Wc1 = (unsigned short*)(ws + off); off = align_up(off + 128 * 256 * 2, 512);
    unsigned short* Wc2 = (unsigned short*)(ws + off); off = align_up(off + 128 * 256 * 2, 512);
    unsigned short* W3c = (unsigned short*)(ws + off); off = align_up(off + 16 * 128 * 2, 512);
    int* csr_src = (int*)(ws + off);    off = align_up(off + (size_t)E * 4, 512);
    float* slotA = (float*)(ws + off);  off = align_up(off + (size_t)N * 128 * 4, 512);
    float* slotB = (float*)(ws + off);  off = align_up(off + (size_t)N * 128 * 4, 512);
    uint2* h1b = (uint2*)(ws + off);    off = align_up(off + (size_t)N * 128 * 2, 512);
    // aliases (lifetimes disjoint):
    //  slotA: partial ushort [count..fill] (19.2MB); xb [pack..agg_gemm1] (25.6MB)
    //  slotB: bkt [partition..fill] (13.44MB); zg+zs [agg_gemm2..out] (4MB)
    unsigned short* partial = (unsigned short*)slotA;
    const int cap = 210000;
    int* bkt = (int*)slotB;
    uint2* xb = (uint2*)slotA;          // written after fill (partial dead)
    unsigned short* zg = (unsigned short*)slotB;
    float* zs = (float*)((char*)slotB + align_up((size_t)N * 8 * 2, 512));
    (void)ws_size;

    // --- CSR build: radix partition + LDS histogram, no per-edge global atomics
    const int npg = (N + G_PART - 1) / G_PART;       // 6250
    const int build_grid = G_PART * B_PART;          // 1536 = 6 blocks/CU

    hipMemsetAsync(gcur, 0, G_PART * 4, stream);
    partition_edges<<<A_BLOCKS, 256, 0, stream>>>(src, dst, E, bkt, gcur, cap, npg);
    count_hist<<<build_grid, 256, 0, stream>>>(bkt, gcur, cap, partial, npg, N);
    scan_partials<<<(N + 255) / 256, 256, 0, stream>>>(partial, cnt, npg, N);

    const int nscan = (N + SCHUNK - 1) / SCHUNK;
    scan_blocks<<<nscan, 256, 0, stream>>>(cnt, row_off, block_sums, N);
    scan_sums<<<1, 256, 0, stream>>>(block_sums, nscan, row_off, N);
    scan_add<<<nscan, 256, 0, stream>>>(row_off, block_sums, N);

    fill_hist<<<build_grid, 256, 0, stream>>>(bkt, gcur, cap, partial, row_off,
                                              csr_src, npg, N);

    // packs (xb after fill: partial slot is free)
    const int n4 = N * 32;
    pack_bf16<<<(n4 + 255) / 256, 256, 0, stream>>>(x, xb, n4);
    pack_weights<<<(65536 + 2048 + 255) / 256, 256, 0, stream>>>(
        Wl1, Wr1, Wl2, Wr2, Wl3, Wr3, Wc1, Wc2, W3c);

    int fusedGrid = (N + 15) / 16;   // 6250 blocks

    // layer 1: fused gather+GEMM -> h1b (bf16)
    agg_gemm<<<fusedGrid, 256, 0, stream>>>(
        (const uint*)xb, (const unsigned short*)xb, row_off, csr_src, Wc1, b1,
        (unsigned short*)h1b, 0, nullptr, nullptr, nullptr, nullptr, N, 1);
    // layer 2: fused gather+GEMM+lin3 -> zg (bf16) + zs (fp32); h2 never stored
    agg_gemm<<<fusedGrid, 256, 0, stream>>>(
        (const uint*)h1b, (const unsigned short*)h1b, row_off, csr_src, Wc2, b2,
        nullptr, 1, W3c, b3, zg, zs, N, 1);
    // final
    out_kernel<<<(N * 8 + 255) / 256, 256, 0, stream>>>(zg, zs, row_off, csr_src,
                                                        (float*)d_out, N);
}